// Round 1
// baseline (597.392 us; speedup 1.0000x reference)
//
#include <hip/hip_runtime.h>

#define BS   512
#define NPTS 18
#define CH   2048
#define EPSF 1e-12f
#define BNS  0.9999950000374997f   // 1/sqrt(1+1e-5)

// ---------------------------------------------------------------------------
// Kernel 1: per-batch small ops. One block per batch, 256 threads.
// Stages x[b] (18x2048 f32 = 147KB) in LDS; computes z1, z2, all 4 distance
// outputs, enc/dec, and u_pre = enc^T @ x.
// ---------------------------------------------------------------------------
__global__ __launch_bounds__(256) void k1_batch(
    const float* __restrict__ x, const float* __restrict__ pc,
    const float* __restrict__ w1, const float* __restrict__ b1,
    const float* __restrict__ w2a, const float* __restrict__ b2a,
    const float* __restrict__ g2, const float* __restrict__ be2,
    const float* __restrict__ w2b, const float* __restrict__ b2b,
    float* __restrict__ d21, float* __restrict__ d11,
    float* __restrict__ d22, float* __restrict__ d12,
    float* __restrict__ u_pre, float* __restrict__ dec_out)
{
  __shared__ float lx[NPTS*CH];          // 147456 B
  __shared__ float G[NPTS*NPTS];
  __shared__ float l1[NPTS*3], l2[NPTS*3];
  __shared__ float z1s[NPTS*3], z2s[NPTS*3], encs[NPTS*3];
  __shared__ float pcs[NPTS*4], ycs[NPTS], xcs[NPTS];
  __shared__ float red[4*NPTS*3];
  __shared__ float n1inv[NPTS], n2inv[NPTS], rinv[NPTS], colinv[3];

  const int b = blockIdx.x, tid = threadIdx.x;
  const int lane = tid & 63, wv = tid >> 6;

  // ---- Phase A: load x[b] and pc[b] ----
  {
    const float4* xb4 = (const float4*)(x + (size_t)b*NPTS*CH);
    float4* lx4 = (float4*)lx;
    for (int i = tid; i < NPTS*CH/4; i += 256) lx4[i] = xb4[i];
    for (int i = tid; i < NPTS*4; i += 256) pcs[i] = pc[(size_t)b*NPTS*4 + i];
    if (tid < NPTS) {
      const float* p = pc + (size_t)b*NPTS*4 + tid*4;
      ycs[tid] = p[0] + floorf(p[2]*0.5f);
      xcs[tid] = p[1] + floorf(p[3]*0.5f);
    }
  }
  __syncthreads();   // S1

  // ---- Phase B: Gram pairs (m<=n) + x.w1 logits, one wave per dot ----
  for (int j = wv; j < 171; j += 4) {
    int n = (int)((sqrtf(8.f*(float)j + 1.f) - 1.f)*0.5f);
    while ((n+1)*(n+2)/2 <= j) ++n;
    while (n*(n+1)/2 > j) --n;
    int m = j - n*(n+1)/2;
    const float* r1 = lx + n*CH;
    const float* r2 = lx + m*CH;
    float a0=0.f,a1=0.f,a2=0.f,a3=0.f;
    #pragma unroll
    for (int t = 0; t < 8; t++) {
      int base = lane + t*256;
      a0 = fmaf(r1[base],     r2[base],     a0);
      a1 = fmaf(r1[base+64],  r2[base+64],  a1);
      a2 = fmaf(r1[base+128], r2[base+128], a2);
      a3 = fmaf(r1[base+192], r2[base+192], a3);
    }
    float acc = (a0+a1)+(a2+a3);
    #pragma unroll
    for (int off = 32; off; off >>= 1) acc += __shfl_xor(acc, off);
    if (lane == 0) { G[n*NPTS+m] = acc; G[m*NPTS+n] = acc; }
  }
  for (int j = wv; j < 54; j += 4) {
    int n = j/3, k = j - 3*n;
    const float* r1 = lx + n*CH;
    const float* r2 = w1 + k*CH;
    float a0=0.f,a1=0.f,a2=0.f,a3=0.f;
    #pragma unroll
    for (int t = 0; t < 8; t++) {
      int base = lane + t*256;
      a0 = fmaf(r1[base],     r2[base],     a0);
      a1 = fmaf(r1[base+64],  r2[base+64],  a1);
      a2 = fmaf(r1[base+128], r2[base+128], a2);
      a3 = fmaf(r1[base+192], r2[base+192], a3);
    }
    float acc = (a0+a1)+(a2+a3);
    #pragma unroll
    for (int off = 32; off; off >>= 1) acc += __shfl_xor(acc, off);
    if (lane == 0) l1[j] = acc;
  }

  // ---- Phase B2: z2 logits from pc (h fused, never materialized) ----
  {
    float p[NPTS][3];
    #pragma unroll
    for (int n = 0; n < NPTS; n++) { p[n][0]=0.f; p[n][1]=0.f; p[n][2]=0.f; }
    for (int c = tid; c < CH; c += 256) {
      const float4 wa = *(const float4*)(w2a + (size_t)c*4);
      const float bb = b2a[c];
      const float gg = g2[c]*BNS, be = be2[c];
      const float wb0 = w2b[c], wb1 = w2b[CH+c], wb2 = w2b[2*CH+c];
      #pragma unroll
      for (int n = 0; n < NPTS; n++) {
        float v = fmaf(pcs[n*4+3], wa.w,
                  fmaf(pcs[n*4+2], wa.z,
                  fmaf(pcs[n*4+1], wa.y,
                  fmaf(pcs[n*4+0], wa.x, bb))));
        float h = fmaxf(fmaf(v, gg, be), 0.f);
        p[n][0] = fmaf(h, wb0, p[n][0]);
        p[n][1] = fmaf(h, wb1, p[n][1]);
        p[n][2] = fmaf(h, wb2, p[n][2]);
      }
    }
    #pragma unroll
    for (int n = 0; n < NPTS; n++)
      #pragma unroll
      for (int k = 0; k < 3; k++) {
        float v = p[n][k];
        #pragma unroll
        for (int off = 32; off; off >>= 1) v += __shfl_xor(v, off);
        if (lane == 0) red[wv*54 + n*3 + k] = v;
      }
  }
  __syncthreads();   // S2
  if (tid < 54) l2[tid] = red[tid] + red[54+tid] + red[108+tid] + red[162+tid] + b2b[tid%3];
  __syncthreads();   // S3

  // ---- Phase C: softmaxes, norms, dec ----
  if (tid < NPTS) {
    int n = tid;
    float a0 = l1[n*3+0] + b1[0], a1 = l1[n*3+1] + b1[1], a2 = l1[n*3+2] + b1[2];
    float mx = fmaxf(a0, fmaxf(a1, a2));
    float e0 = expf(a0-mx), e1 = expf(a1-mx), e2 = expf(a2-mx);
    float inv = 1.f/(e0+e1+e2);
    float z10 = e0*inv, z11 = e1*inv, z12 = e2*inv;
    z1s[n*3+0]=z10; z1s[n*3+1]=z11; z1s[n*3+2]=z12;
    n1inv[n] = 1.f/fmaxf(sqrtf(z10*z10+z11*z11+z12*z12), EPSF);

    float c0 = l2[n*3+0], c1 = l2[n*3+1], c2 = l2[n*3+2];
    mx = fmaxf(c0, fmaxf(c1, c2));
    e0 = expf(c0-mx); e1 = expf(c1-mx); e2 = expf(c2-mx);
    inv = 1.f/(e0+e1+e2);
    float z20 = e0*inv, z21 = e1*inv, z22 = e2*inv;
    z2s[n*3+0]=z20; z2s[n*3+1]=z21; z2s[n*3+2]=z22;
    n2inv[n] = 1.f/fmaxf(sqrtf(z20*z20+z21*z21+z22*z22), EPSF);

    float zr0 = z10+z20, zr1 = z11+z21, zr2 = z12+z22;
    float rinvv = 1.f/((zr0+zr1+zr2) + EPSF);
    dec_out[(size_t)b*54 + n*3 + 0] = zr0*rinvv;
    dec_out[(size_t)b*54 + n*3 + 1] = zr1*rinvv;
    dec_out[(size_t)b*54 + n*3 + 2] = zr2*rinvv;

    rinv[n] = 1.f/fmaxf(sqrtf(G[n*NPTS+n]), EPSF);
  }
  __syncthreads();   // S4

  if (tid < 3) {
    float s = 0.f;
    #pragma unroll
    for (int n = 0; n < NPTS; n++) s += z1s[n*3+tid] + z2s[n*3+tid];
    colinv[tid] = 1.f/(s + EPSF);
  }
  // distance outputs (324 entries each, >256 threads worth -> loop)
  for (int t = tid; t < NPTS*NPTS; t += 256) {
    int n = t/NPTS, m = t - n*NPTS;
    float dd21 = (z1s[n*3]*z1s[m*3] + z1s[n*3+1]*z1s[m*3+1] + z1s[n*3+2]*z1s[m*3+2])
                 * n1inv[n]*n1inv[m];
    float dd22 = (z2s[n*3]*z2s[m*3] + z2s[n*3+1]*z2s[m*3+1] + z2s[n*3+2]*z2s[m*3+2])
                 * n2inv[n]*n2inv[m];
    float dd11 = G[t] * rinv[n]*rinv[m];
    float dyv = ycs[m]-ycs[n], dxv = xcs[m]-xcs[n];
    float r = dxv*dxv + dyv*dyv;
    float dd12 = 1.f - 2.f*((r > 0.f) ? sqrtf(r) : 0.f);
    size_t o = (size_t)b*NPTS*NPTS + t;
    d21[o] = dd21; d11[o] = dd11; d22[o] = dd22; d12[o] = dd12;
  }
  __syncthreads();   // S5 (colinv ready)
  if (tid < 54) encs[tid] = (z1s[tid]+z2s[tid])*colinv[tid%3];
  __syncthreads();   // S6

  // ---- Phase E: u_pre[k,c] = sum_n enc[n,k]*x[n,c] ----
  for (int c = tid; c < CH; c += 256) {
    float acc0=0.f, acc1=0.f, acc2=0.f;
    #pragma unroll
    for (int n = 0; n < NPTS; n++) {
      float xv = lx[n*CH + c];
      acc0 = fmaf(encs[n*3+0], xv, acc0);
      acc1 = fmaf(encs[n*3+1], xv, acc1);
      acc2 = fmaf(encs[n*3+2], xv, acc2);
    }
    u_pre[((size_t)b*3+0)*CH + c] = acc0;
    u_pre[((size_t)b*3+1)*CH + c] = acc1;
    u_pre[((size_t)b*3+2)*CH + c] = acc2;
  }
}

// ---------------------------------------------------------------------------
// GEMM: C[m,d] = sum_c A[m,c]*B[d,c]  (A: 1536x2048, B: 2048x2048 row-major)
// FUSE=1: C = relu((C + bias)*gamma*BNS + beta)
// Tile 64x128, BK=16, 256 threads, 4x8 micro-tile. LDS K-major (transposed)
// so the inner loop is float4 LDS reads.
// ---------------------------------------------------------------------------
template<int FUSE>
__global__ __launch_bounds__(256) void gemm_abt(
    const float* __restrict__ A, const float* __restrict__ B,
    float* __restrict__ Cout, const float* __restrict__ bias,
    const float* __restrict__ gamma, const float* __restrict__ beta)
{
  __shared__ float As[16*68];    // [kk][row(64)+pad4]
  __shared__ float Bs[16*132];   // [kk][col(128)+pad4]
  const int tid = threadIdx.x;
  const int tx = tid & 15, ty = tid >> 4;
  const int mb = blockIdx.x % 24, nb = blockIdx.x / 24;
  const int lrow = tid >> 2, lc4 = tid & 3;
  const float* Ag  = A + ((size_t)(mb*64 + lrow))*2048 + lc4*4;
  const float* Bg0 = B + ((size_t)(nb*128 + lrow))*2048 + lc4*4;
  const float* Bg1 = Bg0 + (size_t)64*2048;

  float acc[4][8];
  #pragma unroll
  for (int i = 0; i < 4; i++)
    #pragma unroll
    for (int j = 0; j < 8; j++) acc[i][j] = 0.f;

  for (int k0 = 0; k0 < 2048; k0 += 16) {
    float4 av  = *(const float4*)(Ag  + k0);
    float4 bv0 = *(const float4*)(Bg0 + k0);
    float4 bv1 = *(const float4*)(Bg1 + k0);
    __syncthreads();
    As[(lc4*4+0)*68 + lrow] = av.x;
    As[(lc4*4+1)*68 + lrow] = av.y;
    As[(lc4*4+2)*68 + lrow] = av.z;
    As[(lc4*4+3)*68 + lrow] = av.w;
    Bs[(lc4*4+0)*132 + lrow] = bv0.x;
    Bs[(lc4*4+1)*132 + lrow] = bv0.y;
    Bs[(lc4*4+2)*132 + lrow] = bv0.z;
    Bs[(lc4*4+3)*132 + lrow] = bv0.w;
    Bs[(lc4*4+0)*132 + 64 + lrow] = bv1.x;
    Bs[(lc4*4+1)*132 + 64 + lrow] = bv1.y;
    Bs[(lc4*4+2)*132 + 64 + lrow] = bv1.z;
    Bs[(lc4*4+3)*132 + 64 + lrow] = bv1.w;
    __syncthreads();
    #pragma unroll
    for (int kk = 0; kk < 16; kk++) {
      float4 a  = *(const float4*)(As + kk*68 + ty*4);
      float4 b0 = *(const float4*)(Bs + kk*132 + tx*8);
      float4 b1 = *(const float4*)(Bs + kk*132 + tx*8 + 4);
      float aa[4] = {a.x, a.y, a.z, a.w};
      float bb[8] = {b0.x, b0.y, b0.z, b0.w, b1.x, b1.y, b1.z, b1.w};
      #pragma unroll
      for (int i = 0; i < 4; i++)
        #pragma unroll
        for (int j = 0; j < 8; j++)
          acc[i][j] = fmaf(aa[i], bb[j], acc[i][j]);
    }
  }

  const int col0 = nb*128 + tx*8;
  float4 bi0 = make_float4(0,0,0,0), bi1 = bi0, ga0 = bi0, ga1 = bi0, bt0 = bi0, bt1 = bi0;
  if (FUSE) {
    bi0 = *(const float4*)(bias + col0);  bi1 = *(const float4*)(bias + col0 + 4);
    ga0 = *(const float4*)(gamma + col0); ga1 = *(const float4*)(gamma + col0 + 4);
    bt0 = *(const float4*)(beta + col0);  bt1 = *(const float4*)(beta + col0 + 4);
  }
  #pragma unroll
  for (int i = 0; i < 4; i++) {
    int m = mb*64 + ty*4 + i;
    float o[8];
    #pragma unroll
    for (int j = 0; j < 8; j++) o[j] = acc[i][j];
    if (FUSE) {
      o[0] = fmaxf(fmaf(o[0] + bi0.x, ga0.x*BNS, bt0.x), 0.f);
      o[1] = fmaxf(fmaf(o[1] + bi0.y, ga0.y*BNS, bt0.y), 0.f);
      o[2] = fmaxf(fmaf(o[2] + bi0.z, ga0.z*BNS, bt0.z), 0.f);
      o[3] = fmaxf(fmaf(o[3] + bi0.w, ga0.w*BNS, bt0.w), 0.f);
      o[4] = fmaxf(fmaf(o[4] + bi1.x, ga1.x*BNS, bt1.x), 0.f);
      o[5] = fmaxf(fmaf(o[5] + bi1.y, ga1.y*BNS, bt1.y), 0.f);
      o[6] = fmaxf(fmaf(o[6] + bi1.z, ga1.z*BNS, bt1.z), 0.f);
      o[7] = fmaxf(fmaf(o[7] + bi1.w, ga1.w*BNS, bt1.w), 0.f);
    }
    *(float4*)(Cout + (size_t)m*2048 + col0)     = make_float4(o[0],o[1],o[2],o[3]);
    *(float4*)(Cout + (size_t)m*2048 + col0 + 4) = make_float4(o[4],o[5],o[6],o[7]);
  }
}

// ---------------------------------------------------------------------------
// Epilogue: y[b,n,d] = relu((sum_k dec[b,n,k]*V[b,k,d] + b3[d])*g3s[d]+be3[d]) + x
// One block per batch.
// ---------------------------------------------------------------------------
__global__ __launch_bounds__(256) void k_epi(
    const float* __restrict__ x, const float* __restrict__ V,
    const float* __restrict__ dec, const float* __restrict__ b3,
    const float* __restrict__ g3, const float* __restrict__ be3,
    float* __restrict__ y)
{
  __shared__ float4 lv[3*512];
  __shared__ float4 lmul[512], ladd[512];
  __shared__ float ld[54];
  const int b = blockIdx.x, tid = threadIdx.x;

  const float4* v4 = (const float4*)(V + (size_t)b*3*CH);
  for (int i = tid; i < 1536; i += 256) lv[i] = v4[i];
  const float4* g34  = (const float4*)g3;
  const float4* b34  = (const float4*)b3;
  const float4* be34 = (const float4*)be3;
  for (int i = tid; i < 512; i += 256) {
    float4 g = g34[i], bb = b34[i], be = be34[i];
    float4 mu, ad;
    mu.x = g.x*BNS; mu.y = g.y*BNS; mu.z = g.z*BNS; mu.w = g.w*BNS;
    ad.x = fmaf(bb.x, mu.x, be.x); ad.y = fmaf(bb.y, mu.y, be.y);
    ad.z = fmaf(bb.z, mu.z, be.z); ad.w = fmaf(bb.w, mu.w, be.w);
    lmul[i] = mu; ladd[i] = ad;
  }
  if (tid < 54) ld[tid] = dec[(size_t)b*54 + tid];
  __syncthreads();

  for (int r = 0; r < NPTS; r++) {
    float d0 = ld[r*3+0], d1 = ld[r*3+1], d2 = ld[r*3+2];
    const float4* xr = (const float4*)(x + ((size_t)b*NPTS + r)*CH);
    float4* yr = (float4*)(y + ((size_t)b*NPTS + r)*CH);
    for (int i = tid; i < 512; i += 256) {
      float4 v0 = lv[i], v1 = lv[512+i], v2 = lv[1024+i];
      float4 mu = lmul[i], ad = ladd[i], xa = xr[i];
      float4 o;
      o.x = fmaxf(fmaf(fmaf(d0,v0.x, fmaf(d1,v1.x, d2*v2.x)), mu.x, ad.x), 0.f) + xa.x;
      o.y = fmaxf(fmaf(fmaf(d0,v0.y, fmaf(d1,v1.y, d2*v2.y)), mu.y, ad.y), 0.f) + xa.y;
      o.z = fmaxf(fmaf(fmaf(d0,v0.z, fmaf(d1,v1.z, d2*v2.z)), mu.z, ad.z), 0.f) + xa.z;
      o.w = fmaxf(fmaf(fmaf(d0,v0.w, fmaf(d1,v1.w, d2*v2.w)), mu.w, ad.w), 0.f) + xa.w;
      yr[i] = o;
    }
  }
}

// ---------------------------------------------------------------------------
extern "C" void kernel_launch(void* const* d_in, const int* in_sizes, int n_in,
                              void* d_out, int out_size, void* d_ws, size_t ws_size,
                              hipStream_t stream) {
  const float* x   = (const float*)d_in[0];
  const float* pc  = (const float*)d_in[1];
  const float* w1  = (const float*)d_in[2];
  const float* b1  = (const float*)d_in[3];
  const float* w2a = (const float*)d_in[4];
  const float* b2a = (const float*)d_in[5];
  const float* g2  = (const float*)d_in[6];
  const float* be2 = (const float*)d_in[7];
  const float* w2b = (const float*)d_in[8];
  const float* b2b = (const float*)d_in[9];
  const float* wc  = (const float*)d_in[10];
  const float* bc  = (const float*)d_in[11];
  const float* gc  = (const float*)d_in[12];
  const float* bec = (const float*)d_in[13];
  const float* w3  = (const float*)d_in[14];
  const float* b3  = (const float*)d_in[15];
  const float* g3  = (const float*)d_in[16];
  const float* be3 = (const float*)d_in[17];

  float* out = (float*)d_out;
  float* y   = out;
  float* d21 = out + (size_t)BS*NPTS*CH;
  float* d11 = d21 + (size_t)BS*NPTS*NPTS;
  float* d22 = d11 + (size_t)BS*NPTS*NPTS;
  float* d12 = d22 + (size_t)BS*NPTS*NPTS;

  // u_pre and u are dead before the epilogue writes y -> reuse the y region.
  float* u_pre = y;                          // 512*3*2048 floats
  float* u     = y + (size_t)BS*3*CH;        // next 512*3*2048 floats
  // V and dec must survive into the (grid-wide) epilogue -> workspace.
  float* V     = (float*)d_ws;               // 512*3*2048 floats
  float* decb  = V + (size_t)BS*3*CH;        // 512*54 floats

  k1_batch<<<BS, 256, 0, stream>>>(x, pc, w1, b1, w2a, b2a, g2, be2, w2b, b2b,
                                   d21, d11, d22, d12, u_pre, decb);
  gemm_abt<1><<<24*16, 256, 0, stream>>>(u_pre, wc, u, bc, gc, bec);
  gemm_abt<0><<<24*16, 256, 0, stream>>>(u, w3, V, nullptr, nullptr, nullptr);
  k_epi<<<BS, 256, 0, stream>>>(x, V, decb, b3, g3, be3, y);
}

// Round 2
// 259.201 us; speedup vs baseline: 2.3047x; 2.3047x over previous
//
#include <hip/hip_runtime.h>

#define BS   512
#define NPTS 18
#define CH   2048
#define EPSF 1e-12f
#define BNS  0.9999950000374997f   // 1/sqrt(1+1e-5)

typedef unsigned short ushort_t;
typedef __attribute__((ext_vector_type(8))) short  bfrag;   // 8 bf16 (4 VGPRs)
typedef __attribute__((ext_vector_type(4))) float  f32x4v;  // MFMA C/D

__device__ inline ushort_t bf16_rne(float f) {
  union { float f; unsigned int u; } c; c.f = f;
  unsigned int u = c.u;
  u += 0x7fffu + ((u >> 16) & 1u);
  return (ushort_t)(u >> 16);
}

// ---------------------------------------------------------------------------
// f32 -> bf16 cast (vectorized), n4 = count/4
// ---------------------------------------------------------------------------
__global__ __launch_bounds__(256) void f32_to_bf16_k(
    const float* __restrict__ in, ushort_t* __restrict__ out, int n4)
{
  int i = blockIdx.x * 256 + threadIdx.x;
  if (i < n4) {
    float4 v = ((const float4*)in)[i];
    ushort4 o;
    o.x = bf16_rne(v.x); o.y = bf16_rne(v.y);
    o.z = bf16_rne(v.z); o.w = bf16_rne(v.w);
    ((ushort4*)out)[i] = o;
  }
}

// ---------------------------------------------------------------------------
// Kernel 1: per-batch small ops. One block per batch, 256 threads.
// u_pre is now written as bf16 (feeds the MFMA GEMM).
// ---------------------------------------------------------------------------
__global__ __launch_bounds__(256) void k1_batch(
    const float* __restrict__ x, const float* __restrict__ pc,
    const float* __restrict__ w1, const float* __restrict__ b1,
    const float* __restrict__ w2a, const float* __restrict__ b2a,
    const float* __restrict__ g2, const float* __restrict__ be2,
    const float* __restrict__ w2b, const float* __restrict__ b2b,
    float* __restrict__ d21, float* __restrict__ d11,
    float* __restrict__ d22, float* __restrict__ d12,
    ushort_t* __restrict__ u_pre, float* __restrict__ dec_out)
{
  __shared__ float lx[NPTS*CH];          // 147456 B
  __shared__ float G[NPTS*NPTS];
  __shared__ float l1[NPTS*3], l2[NPTS*3];
  __shared__ float z1s[NPTS*3], z2s[NPTS*3], encs[NPTS*3];
  __shared__ float pcs[NPTS*4], ycs[NPTS], xcs[NPTS];
  __shared__ float red[4*NPTS*3];
  __shared__ float n1inv[NPTS], n2inv[NPTS], rinv[NPTS], colinv[3];

  const int b = blockIdx.x, tid = threadIdx.x;
  const int lane = tid & 63, wv = tid >> 6;

  // ---- Phase A: load x[b] and pc[b] ----
  {
    const float4* xb4 = (const float4*)(x + (size_t)b*NPTS*CH);
    float4* lx4 = (float4*)lx;
    for (int i = tid; i < NPTS*CH/4; i += 256) lx4[i] = xb4[i];
    for (int i = tid; i < NPTS*4; i += 256) pcs[i] = pc[(size_t)b*NPTS*4 + i];
    if (tid < NPTS) {
      const float* p = pc + (size_t)b*NPTS*4 + tid*4;
      ycs[tid] = p[0] + floorf(p[2]*0.5f);
      xcs[tid] = p[1] + floorf(p[3]*0.5f);
    }
  }
  __syncthreads();   // S1

  // ---- Phase B: Gram pairs (m<=n) + x.w1 logits, one wave per dot ----
  for (int j = wv; j < 171; j += 4) {
    int n = (int)((sqrtf(8.f*(float)j + 1.f) - 1.f)*0.5f);
    while ((n+1)*(n+2)/2 <= j) ++n;
    while (n*(n+1)/2 > j) --n;
    int m = j - n*(n+1)/2;
    const float* r1 = lx + n*CH;
    const float* r2 = lx + m*CH;
    float a0=0.f,a1=0.f,a2=0.f,a3=0.f;
    #pragma unroll
    for (int t = 0; t < 8; t++) {
      int base = lane + t*256;
      a0 = fmaf(r1[base],     r2[base],     a0);
      a1 = fmaf(r1[base+64],  r2[base+64],  a1);
      a2 = fmaf(r1[base+128], r2[base+128], a2);
      a3 = fmaf(r1[base+192], r2[base+192], a3);
    }
    float acc = (a0+a1)+(a2+a3);
    #pragma unroll
    for (int off = 32; off; off >>= 1) acc += __shfl_xor(acc, off);
    if (lane == 0) { G[n*NPTS+m] = acc; G[m*NPTS+n] = acc; }
  }
  for (int j = wv; j < 54; j += 4) {
    int n = j/3, k = j - 3*n;
    const float* r1 = lx + n*CH;
    const float* r2 = w1 + k*CH;
    float a0=0.f,a1=0.f,a2=0.f,a3=0.f;
    #pragma unroll
    for (int t = 0; t < 8; t++) {
      int base = lane + t*256;
      a0 = fmaf(r1[base],     r2[base],     a0);
      a1 = fmaf(r1[base+64],  r2[base+64],  a1);
      a2 = fmaf(r1[base+128], r2[base+128], a2);
      a3 = fmaf(r1[base+192], r2[base+192], a3);
    }
    float acc = (a0+a1)+(a2+a3);
    #pragma unroll
    for (int off = 32; off; off >>= 1) acc += __shfl_xor(acc, off);
    if (lane == 0) l1[j] = acc;
  }

  // ---- Phase B2: z2 logits from pc (h fused, never materialized) ----
  {
    float p[NPTS][3];
    #pragma unroll
    for (int n = 0; n < NPTS; n++) { p[n][0]=0.f; p[n][1]=0.f; p[n][2]=0.f; }
    for (int c = tid; c < CH; c += 256) {
      const float4 wa = *(const float4*)(w2a + (size_t)c*4);
      const float bb = b2a[c];
      const float gg = g2[c]*BNS, be = be2[c];
      const float wb0 = w2b[c], wb1 = w2b[CH+c], wb2 = w2b[2*CH+c];
      #pragma unroll
      for (int n = 0; n < NPTS; n++) {
        float v = fmaf(pcs[n*4+3], wa.w,
                  fmaf(pcs[n*4+2], wa.z,
                  fmaf(pcs[n*4+1], wa.y,
                  fmaf(pcs[n*4+0], wa.x, bb))));
        float h = fmaxf(fmaf(v, gg, be), 0.f);
        p[n][0] = fmaf(h, wb0, p[n][0]);
        p[n][1] = fmaf(h, wb1, p[n][1]);
        p[n][2] = fmaf(h, wb2, p[n][2]);
      }
    }
    #pragma unroll
    for (int n = 0; n < NPTS; n++)
      #pragma unroll
      for (int k = 0; k < 3; k++) {
        float v = p[n][k];
        #pragma unroll
        for (int off = 32; off; off >>= 1) v += __shfl_xor(v, off);
        if (lane == 0) red[wv*54 + n*3 + k] = v;
      }
  }
  __syncthreads();   // S2
  if (tid < 54) l2[tid] = red[tid] + red[54+tid] + red[108+tid] + red[162+tid] + b2b[tid%3];
  __syncthreads();   // S3

  // ---- Phase C: softmaxes, norms, dec ----
  if (tid < NPTS) {
    int n = tid;
    float a0 = l1[n*3+0] + b1[0], a1 = l1[n*3+1] + b1[1], a2 = l1[n*3+2] + b1[2];
    float mx = fmaxf(a0, fmaxf(a1, a2));
    float e0 = expf(a0-mx), e1 = expf(a1-mx), e2 = expf(a2-mx);
    float inv = 1.f/(e0+e1+e2);
    float z10 = e0*inv, z11 = e1*inv, z12 = e2*inv;
    z1s[n*3+0]=z10; z1s[n*3+1]=z11; z1s[n*3+2]=z12;
    n1inv[n] = 1.f/fmaxf(sqrtf(z10*z10+z11*z11+z12*z12), EPSF);

    float c0 = l2[n*3+0], c1 = l2[n*3+1], c2 = l2[n*3+2];
    mx = fmaxf(c0, fmaxf(c1, c2));
    e0 = expf(c0-mx); e1 = expf(c1-mx); e2 = expf(c2-mx);
    inv = 1.f/(e0+e1+e2);
    float z20 = e0*inv, z21 = e1*inv, z22 = e2*inv;
    z2s[n*3+0]=z20; z2s[n*3+1]=z21; z2s[n*3+2]=z22;
    n2inv[n] = 1.f/fmaxf(sqrtf(z20*z20+z21*z21+z22*z22), EPSF);

    float zr0 = z10+z20, zr1 = z11+z21, zr2 = z12+z22;
    float rinvv = 1.f/((zr0+zr1+zr2) + EPSF);
    dec_out[(size_t)b*54 + n*3 + 0] = zr0*rinvv;
    dec_out[(size_t)b*54 + n*3 + 1] = zr1*rinvv;
    dec_out[(size_t)b*54 + n*3 + 2] = zr2*rinvv;

    rinv[n] = 1.f/fmaxf(sqrtf(G[n*NPTS+n]), EPSF);
  }
  __syncthreads();   // S4

  if (tid < 3) {
    float s = 0.f;
    #pragma unroll
    for (int n = 0; n < NPTS; n++) s += z1s[n*3+tid] + z2s[n*3+tid];
    colinv[tid] = 1.f/(s + EPSF);
  }
  for (int t = tid; t < NPTS*NPTS; t += 256) {
    int n = t/NPTS, m = t - n*NPTS;
    float dd21 = (z1s[n*3]*z1s[m*3] + z1s[n*3+1]*z1s[m*3+1] + z1s[n*3+2]*z1s[m*3+2])
                 * n1inv[n]*n1inv[m];
    float dd22 = (z2s[n*3]*z2s[m*3] + z2s[n*3+1]*z2s[m*3+1] + z2s[n*3+2]*z2s[m*3+2])
                 * n2inv[n]*n2inv[m];
    float dd11 = G[t] * rinv[n]*rinv[m];
    float dyv = ycs[m]-ycs[n], dxv = xcs[m]-xcs[n];
    float r = dxv*dxv + dyv*dyv;
    float dd12 = 1.f - 2.f*((r > 0.f) ? sqrtf(r) : 0.f);
    size_t o = (size_t)b*NPTS*NPTS + t;
    d21[o] = dd21; d11[o] = dd11; d22[o] = dd22; d12[o] = dd12;
  }
  __syncthreads();   // S5
  if (tid < 54) encs[tid] = (z1s[tid]+z2s[tid])*colinv[tid%3];
  __syncthreads();   // S6

  // ---- Phase E: u_pre[k,c] = sum_n enc[n,k]*x[n,c]  (bf16 out) ----
  for (int c = tid; c < CH; c += 256) {
    float acc0=0.f, acc1=0.f, acc2=0.f;
    #pragma unroll
    for (int n = 0; n < NPTS; n++) {
      float xv = lx[n*CH + c];
      acc0 = fmaf(encs[n*3+0], xv, acc0);
      acc1 = fmaf(encs[n*3+1], xv, acc1);
      acc2 = fmaf(encs[n*3+2], xv, acc2);
    }
    u_pre[((size_t)b*3+0)*CH + c] = bf16_rne(acc0);
    u_pre[((size_t)b*3+1)*CH + c] = bf16_rne(acc1);
    u_pre[((size_t)b*3+2)*CH + c] = bf16_rne(acc2);
  }
}

// ---------------------------------------------------------------------------
// bf16 MFMA GEMM (m97 structure): C[m,d] = sum_c A[m,c]*B[d,c]
// A: [1536][2048] bf16, B: [2048][2048] bf16 (weight layout = B^T form).
// 128x128 tile, BK=64, 256 threads (4 waves), wave = 64x64 quadrant,
// 4x4 fragments of mfma_f32_16x16x32_bf16. Linear LDS + global_load_lds w16.
// MODE 1: out = bf16( relu((acc+bias)*gamma*BNS+beta) )   [feeds GEMM2]
// MODE 0: out = f32 acc                                    [V]
// ---------------------------------------------------------------------------
#define GM 1536
#define GK 2048
#define GN 2048

template<int MODE>
__global__ __launch_bounds__(256) void gemm_mfma(
    const ushort_t* __restrict__ A, const ushort_t* __restrict__ B,
    void* __restrict__ Cout, const float* __restrict__ bias,
    const float* __restrict__ gamma, const float* __restrict__ beta)
{
  __shared__ ushort_t Asm[128*64];   // 16 KB, [row][k] linear
  __shared__ ushort_t Bsm[128*64];   // 16 KB, [col][k] linear
  const int tid  = threadIdx.x;
  const int lane = tid & 63, wv = tid >> 6;
  const int mb = blockIdx.x % (GM/128), nb = blockIdx.x / (GM/128);
  const int wr = (wv >> 1) * 64, wc = (wv & 1) * 64;   // wave quadrant

  f32x4v acc[4][4];
  #pragma unroll
  for (int m = 0; m < 4; m++)
    #pragma unroll
    for (int n = 0; n < 4; n++)
      acc[m][n] = (f32x4v){0.f, 0.f, 0.f, 0.f};

  const int ldrow = tid >> 3;        // 0..31 within each 32-row chunk
  const int ldcol = (tid & 7) * 8;   // element col within BK=64
  const ushort_t* Ag = A + (size_t)(mb*128 + 0)*GK;
  const ushort_t* Bg = B + (size_t)(nb*128 + 0)*GK;
  const int r15 = lane & 15, khi = lane >> 4;

  for (int k0 = 0; k0 < GK; k0 += 64) {
    __syncthreads();   // previous tile's compute done before overwrite
    #pragma unroll
    for (int i = 0; i < 4; i++) {
      const ushort_t* ga = Ag + (size_t)(i*32 + ldrow)*GK + k0 + ldcol;
      const ushort_t* gb = Bg + (size_t)(i*32 + ldrow)*GK + k0 + ldcol;
      __builtin_amdgcn_global_load_lds(
          (const __attribute__((address_space(1))) void*)ga,
          (__attribute__((address_space(3))) void*)(Asm + i*2048 + wv*512),
          16, 0, 0);
      __builtin_amdgcn_global_load_lds(
          (const __attribute__((address_space(1))) void*)gb,
          (__attribute__((address_space(3))) void*)(Bsm + i*2048 + wv*512),
          16, 0, 0);
    }
    asm volatile("s_waitcnt vmcnt(0)" ::: "memory");
    __syncthreads();   // staging visible to all waves

    #pragma unroll
    for (int ks = 0; ks < 2; ks++) {
      bfrag af[4], bfv[4];
      #pragma unroll
      for (int m = 0; m < 4; m++)
        af[m] = *(const bfrag*)(Asm + (wr + m*16 + r15)*64 + ks*32 + khi*8);
      #pragma unroll
      for (int n = 0; n < 4; n++)
        bfv[n] = *(const bfrag*)(Bsm + (wc + n*16 + r15)*64 + ks*32 + khi*8);
      #pragma unroll
      for (int m = 0; m < 4; m++)
        #pragma unroll
        for (int n = 0; n < 4; n++)
          acc[m][n] = __builtin_amdgcn_mfma_f32_16x16x32_bf16(
              af[m], bfv[n], acc[m][n], 0, 0, 0);
    }
  }

  // ---- epilogue: C/D layout col=lane&15, row=(lane>>4)*4+reg ----
  #pragma unroll
  for (int n = 0; n < 4; n++) {
    const int gc = nb*128 + wc + n*16 + r15;
    float bi = 0.f, ga = 0.f, be = 0.f;
    if (MODE == 1) { bi = bias[gc]; ga = gamma[gc]*BNS; be = beta[gc]; }
    #pragma unroll
    for (int m = 0; m < 4; m++) {
      const int gr0 = mb*128 + wr + m*16 + khi*4;
      #pragma unroll
      for (int r = 0; r < 4; r++) {
        float v = acc[m][n][r];
        if (MODE == 1) {
          v = fmaxf(fmaf(v + bi, ga, be), 0.f);
          ((ushort_t*)Cout)[(size_t)(gr0 + r)*GN + gc] = bf16_rne(v);
        } else {
          ((float*)Cout)[(size_t)(gr0 + r)*GN + gc] = v;
        }
      }
    }
  }
}

// ---------------------------------------------------------------------------
// Epilogue: y[b,n,d] = relu((sum_k dec[b,n,k]*V[b,k,d] + b3[d])*g3s[d]+be3[d]) + x
// ---------------------------------------------------------------------------
__global__ __launch_bounds__(256) void k_epi(
    const float* __restrict__ x, const float* __restrict__ V,
    const float* __restrict__ dec, const float* __restrict__ b3,
    const float* __restrict__ g3, const float* __restrict__ be3,
    float* __restrict__ y)
{
  __shared__ float4 lv[3*512];
  __shared__ float4 lmul[512], ladd[512];
  __shared__ float ld[54];
  const int b = blockIdx.x, tid = threadIdx.x;

  const float4* v4 = (const float4*)(V + (size_t)b*3*CH);
  for (int i = tid; i < 1536; i += 256) lv[i] = v4[i];
  const float4* g34  = (const float4*)g3;
  const float4* b34  = (const float4*)b3;
  const float4* be34 = (const float4*)be3;
  for (int i = tid; i < 512; i += 256) {
    float4 g = g34[i], bb = b34[i], be = be34[i];
    float4 mu, ad;
    mu.x = g.x*BNS; mu.y = g.y*BNS; mu.z = g.z*BNS; mu.w = g.w*BNS;
    ad.x = fmaf(bb.x, mu.x, be.x); ad.y = fmaf(bb.y, mu.y, be.y);
    ad.z = fmaf(bb.z, mu.z, be.z); ad.w = fmaf(bb.w, mu.w, be.w);
    lmul[i] = mu; ladd[i] = ad;
  }
  if (tid < 54) ld[tid] = dec[(size_t)b*54 + tid];
  __syncthreads();

  for (int r = 0; r < NPTS; r++) {
    float d0 = ld[r*3+0], d1 = ld[r*3+1], d2 = ld[r*3+2];
    const float4* xr = (const float4*)(x + ((size_t)b*NPTS + r)*CH);
    float4* yr = (float4*)(y + ((size_t)b*NPTS + r)*CH);
    for (int i = tid; i < 512; i += 256) {
      float4 v0 = lv[i], v1 = lv[512+i], v2 = lv[1024+i];
      float4 mu = lmul[i], ad = ladd[i], xa = xr[i];
      float4 o;
      o.x = fmaxf(fmaf(fmaf(d0,v0.x, fmaf(d1,v1.x, d2*v2.x)), mu.x, ad.x), 0.f) + xa.x;
      o.y = fmaxf(fmaf(fmaf(d0,v0.y, fmaf(d1,v1.y, d2*v2.y)), mu.y, ad.y), 0.f) + xa.y;
      o.z = fmaxf(fmaf(fmaf(d0,v0.z, fmaf(d1,v1.z, d2*v2.z)), mu.z, ad.z), 0.f) + xa.z;
      o.w = fmaxf(fmaf(fmaf(d0,v0.w, fmaf(d1,v1.w, d2*v2.w)), mu.w, ad.w), 0.f) + xa.w;
      yr[i] = o;
    }
  }
}

// ---------------------------------------------------------------------------
extern "C" void kernel_launch(void* const* d_in, const int* in_sizes, int n_in,
                              void* d_out, int out_size, void* d_ws, size_t ws_size,
                              hipStream_t stream) {
  const float* x   = (const float*)d_in[0];
  const float* pc  = (const float*)d_in[1];
  const float* w1  = (const float*)d_in[2];
  const float* b1  = (const float*)d_in[3];
  const float* w2a = (const float*)d_in[4];
  const float* b2a = (const float*)d_in[5];
  const float* g2  = (const float*)d_in[6];
  const float* be2 = (const float*)d_in[7];
  const float* w2b = (const float*)d_in[8];
  const float* b2b = (const float*)d_in[9];
  const float* wc  = (const float*)d_in[10];
  const float* bc  = (const float*)d_in[11];
  const float* gc  = (const float*)d_in[12];
  const float* bec = (const float*)d_in[13];
  const float* w3  = (const float*)d_in[14];
  const float* b3  = (const float*)d_in[15];
  const float* g3  = (const float*)d_in[16];
  const float* be3 = (const float*)d_in[17];

  float* out = (float*)d_out;
  float* y   = out;
  float* d21 = out + (size_t)BS*NPTS*CH;
  float* d11 = d21 + (size_t)BS*NPTS*NPTS;
  float* d22 = d11 + (size_t)BS*NPTS*NPTS;
  float* d12 = d22 + (size_t)BS*NPTS*NPTS;

  // Scratch in the dead-until-epilogue y region (75.5 MB available):
  //   u_pre_bf [1536][2048] bf16 @ 0        (6.29 MB)
  //   u_bf     [1536][2048] bf16 @ 6291456  (6.29 MB)
  //   wc_bf    [2048][2048] bf16 @ 12582912 (8.39 MB)
  //   w3_bf    [2048][2048] bf16 @ 20971520 (8.39 MB)   end = 29.4 MB < 75.5
  char* ybytes = (char*)y;
  ushort_t* u_pre_bf = (ushort_t*)(ybytes + 0);
  ushort_t* u_bf     = (ushort_t*)(ybytes + 6291456);
  ushort_t* wc_bf    = (ushort_t*)(ybytes + 12582912);
  ushort_t* w3_bf    = (ushort_t*)(ybytes + 20971520);

  // V and dec must survive into the epilogue -> workspace.
  float* V    = (float*)d_ws;               // 512*3*2048 floats
  float* decb = V + (size_t)BS*3*CH;        // 512*54 floats

  f32_to_bf16_k<<<(GK*GN/4 + 255)/256, 256, 0, stream>>>(wc, wc_bf, GK*GN/4);
  f32_to_bf16_k<<<(GK*GN/4 + 255)/256, 256, 0, stream>>>(w3, w3_bf, GK*GN/4);
  k1_batch<<<BS, 256, 0, stream>>>(x, pc, w1, b1, w2a, b2a, g2, be2, w2b, b2b,
                                   d21, d11, d22, d12, u_pre_bf, decb);
  gemm_mfma<1><<<(GM/128)*(GN/128), 256, 0, stream>>>(u_pre_bf, wc_bf, u_bf, bc, gc, bec);
  gemm_mfma<0><<<(GM/128)*(GN/128), 256, 0, stream>>>(u_bf, w3_bf, V, nullptr, nullptr, nullptr);
  k_epi<<<BS, 256, 0, stream>>>(x, V, decb, b3, g3, be3, y);
}

// Round 3
// 179.992 us; speedup vs baseline: 3.3190x; 1.4401x over previous
//
#include <hip/hip_runtime.h>

#define BS   512
#define NPTS 18
#define CH   2048
#define EPSF 1e-12f
#define BNS  0.9999950000374997f   // 1/sqrt(1+1e-5)

typedef unsigned short ushort_t;
typedef __attribute__((ext_vector_type(8)))  short bfrag;   // 8 bf16 (4 VGPRs)
typedef __attribute__((ext_vector_type(4)))  float f32x4v;  // MFMA 16x16 C/D
typedef __attribute__((ext_vector_type(16))) float f32x16;  // MFMA 32x32 C/D

__device__ inline ushort_t bf16_rne(float f) {
  union { float f; unsigned int u; } c; c.f = f;
  unsigned int u = c.u;
  u += 0x7fffu + ((u >> 16) & 1u);
  return (ushort_t)(u >> 16);
}
__device__ inline float bf16_to_f(ushort_t s) {
  union { float f; unsigned int u; } c; c.u = ((unsigned int)s) << 16;
  return c.f;
}

// ---------------------------------------------------------------------------
// f32 -> bf16 cast (vectorized), n4 = count/4
// ---------------------------------------------------------------------------
__global__ __launch_bounds__(256) void f32_to_bf16_k(
    const float* __restrict__ in, ushort_t* __restrict__ out, int n4)
{
  int i = blockIdx.x * 256 + threadIdx.x;
  if (i < n4) {
    float4 v = ((const float4*)in)[i];
    ushort4 o;
    o.x = bf16_rne(v.x); o.y = bf16_rne(v.y);
    o.z = bf16_rne(v.z); o.w = bf16_rne(v.w);
    ((ushort4*)out)[i] = o;
  }
}

// ---------------------------------------------------------------------------
// Kernel 1: per-batch small ops. One block per batch, 256 threads (4 waves).
// x[b] staged as bf16 (74KB -> 2 blocks/CU). Wave 0: Gram+l1 via one
// mfma_32x32x16_bf16 chain ([X] x [X;w1]^T). Waves 1-3: z2 logits reduction.
// ---------------------------------------------------------------------------
__global__ __launch_bounds__(256) void k1_batch(
    const float* __restrict__ x, const float* __restrict__ pc,
    const float* __restrict__ w1, const float* __restrict__ b1,
    const float* __restrict__ w2a, const float* __restrict__ b2a,
    const float* __restrict__ g2, const float* __restrict__ be2,
    const float* __restrict__ w2b, const float* __restrict__ b2b,
    float* __restrict__ d21, float* __restrict__ d11,
    float* __restrict__ d22, float* __restrict__ d12,
    ushort_t* __restrict__ u_pre, float* __restrict__ dec_out)
{
  __shared__ __align__(16) ushort_t lxb[NPTS*CH];   // 73728 B (bf16 X)
  __shared__ float G[NPTS*NPTS];
  __shared__ float l1[NPTS*3], l2[NPTS*3];
  __shared__ float z1s[NPTS*3], z2s[NPTS*3], encs[NPTS*3];
  __shared__ float pcs[NPTS*4], ycs[NPTS], xcs[NPTS];
  __shared__ float red[3*NPTS*3];
  __shared__ float n1inv[NPTS], n2inv[NPTS], rinv[NPTS], colinv[3];

  const int b = blockIdx.x, tid = threadIdx.x;
  const int lane = tid & 63, wv = tid >> 6;

  // ---- Phase A: stage x[b] as bf16, load pc[b] ----
  {
    const float4* xb4 = (const float4*)(x + (size_t)b*NPTS*CH);
    for (int i = tid; i < NPTS*CH/4; i += 256) {
      float4 v = xb4[i];
      ushort4 o;
      o.x = bf16_rne(v.x); o.y = bf16_rne(v.y);
      o.z = bf16_rne(v.z); o.w = bf16_rne(v.w);
      *(ushort4*)(lxb + i*4) = o;
    }
    for (int i = tid; i < NPTS*4; i += 256) pcs[i] = pc[(size_t)b*NPTS*4 + i];
    if (tid < NPTS) {
      const float* p = pc + (size_t)b*NPTS*4 + tid*4;
      ycs[tid] = p[0] + floorf(p[2]*0.5f);
      xcs[tid] = p[1] + floorf(p[3]*0.5f);
    }
  }
  __syncthreads();   // S1

  if (wv == 0) {
    // ---- Wave 0: G (18x18) and l1 (18x3) via one 32x32 MFMA chain ----
    const int rc = lane & 31;          // A-row / B-col
    const int kh = lane >> 5;          // k-half (0/1) -> k offset kh*8
    const bool xok = rc < NPTS;
    const bool wok = (rc >= NPTS) && (rc < NPTS+3);
    const float* wp = w1 + (size_t)(wok ? (rc - NPTS) : 0)*CH;
    f32x16 acc0 = {0.f,0.f,0.f,0.f,0.f,0.f,0.f,0.f,0.f,0.f,0.f,0.f,0.f,0.f,0.f,0.f};
    f32x16 acc1 = acc0;
    #pragma unroll 4
    for (int s = 0; s < CH/16; s++) {
      const int k = s*16 + kh*8;
      bfrag xv = {0,0,0,0,0,0,0,0};
      if (xok) xv = *(const bfrag*)(lxb + rc*CH + k);
      bfrag bv = xv;
      if (wok) {
        float4 f0 = *(const float4*)(wp + k);
        float4 f1 = *(const float4*)(wp + k + 4);
        bv[0] = (short)bf16_rne(f0.x); bv[1] = (short)bf16_rne(f0.y);
        bv[2] = (short)bf16_rne(f0.z); bv[3] = (short)bf16_rne(f0.w);
        bv[4] = (short)bf16_rne(f1.x); bv[5] = (short)bf16_rne(f1.y);
        bv[6] = (short)bf16_rne(f1.z); bv[7] = (short)bf16_rne(f1.w);
      }
      if (s & 1) acc1 = __builtin_amdgcn_mfma_f32_32x32x16_bf16(xv, bv, acc1, 0, 0, 0);
      else       acc0 = __builtin_amdgcn_mfma_f32_32x32x16_bf16(xv, bv, acc0, 0, 0, 0);
    }
    // C/D layout: col = lane&31, row = (reg&3) + 8*(reg>>2) + 4*(lane>>5)
    #pragma unroll
    for (int r = 0; r < 16; r++) {
      float v = acc0[r] + acc1[r];
      int orow = (r & 3) + 8*(r >> 2) + 4*kh;
      if (orow < NPTS) {
        if (rc < NPTS)            G[orow*NPTS + rc] = v;
        else if (rc < NPTS + 3)   l1[orow*3 + (rc - NPTS)] = v;
      }
    }
  } else {
    // ---- Waves 1-3: z2 logits (h fused, never materialized), 192 threads ----
    float p[NPTS][3];
    #pragma unroll
    for (int n = 0; n < NPTS; n++) { p[n][0]=0.f; p[n][1]=0.f; p[n][2]=0.f; }
    for (int it = 0; it < 11; it++) {
      int c = (tid - 64) + it*192;
      if (c < CH) {
        const float4 wa = *(const float4*)(w2a + (size_t)c*4);
        const float bb = b2a[c];
        const float gg = g2[c]*BNS, be = be2[c];
        const float wb0 = w2b[c], wb1 = w2b[CH+c], wb2 = w2b[2*CH+c];
        #pragma unroll
        for (int n = 0; n < NPTS; n++) {
          float v = fmaf(pcs[n*4+3], wa.w,
                    fmaf(pcs[n*4+2], wa.z,
                    fmaf(pcs[n*4+1], wa.y,
                    fmaf(pcs[n*4+0], wa.x, bb))));
          float h = fmaxf(fmaf(v, gg, be), 0.f);
          p[n][0] = fmaf(h, wb0, p[n][0]);
          p[n][1] = fmaf(h, wb1, p[n][1]);
          p[n][2] = fmaf(h, wb2, p[n][2]);
        }
      }
    }
    #pragma unroll
    for (int n = 0; n < NPTS; n++)
      #pragma unroll
      for (int k = 0; k < 3; k++) {
        float v = p[n][k];
        #pragma unroll
        for (int off = 32; off; off >>= 1) v += __shfl_xor(v, off);
        if (lane == 0) red[(wv-1)*54 + n*3 + k] = v;
      }
  }
  __syncthreads();   // S2
  if (tid < 54) l2[tid] = red[tid] + red[54+tid] + red[108+tid] + b2b[tid%3];
  __syncthreads();   // S3

  // ---- softmaxes, norms, dec ----
  if (tid < NPTS) {
    int n = tid;
    float a0 = l1[n*3+0] + b1[0], a1 = l1[n*3+1] + b1[1], a2 = l1[n*3+2] + b1[2];
    float mx = fmaxf(a0, fmaxf(a1, a2));
    float e0 = expf(a0-mx), e1 = expf(a1-mx), e2 = expf(a2-mx);
    float inv = 1.f/(e0+e1+e2);
    float z10 = e0*inv, z11 = e1*inv, z12 = e2*inv;
    z1s[n*3+0]=z10; z1s[n*3+1]=z11; z1s[n*3+2]=z12;
    n1inv[n] = 1.f/fmaxf(sqrtf(z10*z10+z11*z11+z12*z12), EPSF);

    float c0 = l2[n*3+0], c1 = l2[n*3+1], c2 = l2[n*3+2];
    mx = fmaxf(c0, fmaxf(c1, c2));
    e0 = expf(c0-mx); e1 = expf(c1-mx); e2 = expf(c2-mx);
    inv = 1.f/(e0+e1+e2);
    float z20 = e0*inv, z21 = e1*inv, z22 = e2*inv;
    z2s[n*3+0]=z20; z2s[n*3+1]=z21; z2s[n*3+2]=z22;
    n2inv[n] = 1.f/fmaxf(sqrtf(z20*z20+z21*z21+z22*z22), EPSF);

    float zr0 = z10+z20, zr1 = z11+z21, zr2 = z12+z22;
    float rinvv = 1.f/((zr0+zr1+zr2) + EPSF);
    dec_out[(size_t)b*54 + n*3 + 0] = zr0*rinvv;
    dec_out[(size_t)b*54 + n*3 + 1] = zr1*rinvv;
    dec_out[(size_t)b*54 + n*3 + 2] = zr2*rinvv;

    rinv[n] = 1.f/fmaxf(sqrtf(G[n*NPTS+n]), EPSF);
  }
  __syncthreads();   // S4

  if (tid < 3) {
    float s = 0.f;
    #pragma unroll
    for (int n = 0; n < NPTS; n++) s += z1s[n*3+tid] + z2s[n*3+tid];
    colinv[tid] = 1.f/(s + EPSF);
  }
  for (int t = tid; t < NPTS*NPTS; t += 256) {
    int n = t/NPTS, m = t - n*NPTS;
    float dd21 = (z1s[n*3]*z1s[m*3] + z1s[n*3+1]*z1s[m*3+1] + z1s[n*3+2]*z1s[m*3+2])
                 * n1inv[n]*n1inv[m];
    float dd22 = (z2s[n*3]*z2s[m*3] + z2s[n*3+1]*z2s[m*3+1] + z2s[n*3+2]*z2s[m*3+2])
                 * n2inv[n]*n2inv[m];
    float dd11 = G[t] * rinv[n]*rinv[m];
    float dyv = ycs[m]-ycs[n], dxv = xcs[m]-xcs[n];
    float r = dxv*dxv + dyv*dyv;
    float dd12 = 1.f - 2.f*((r > 0.f) ? sqrtf(r) : 0.f);
    size_t o = (size_t)b*NPTS*NPTS + t;
    d21[o] = dd21; d11[o] = dd11; d22[o] = dd22; d12[o] = dd12;
  }
  __syncthreads();   // S5
  if (tid < 54) encs[tid] = (z1s[tid]+z2s[tid])*colinv[tid%3];
  __syncthreads();   // S6

  // ---- u_pre[k,c] = sum_n enc[n,k]*x[n,c]  (bf16 in LDS, bf16 out) ----
  {
    const int c0 = tid*8;                 // 256 threads x 8 ch = 2048
    float av0[8], av1[8], av2[8];
    #pragma unroll
    for (int j = 0; j < 8; j++) { av0[j]=0.f; av1[j]=0.f; av2[j]=0.f; }
    for (int n = 0; n < NPTS; n++) {
      bfrag xv = *(const bfrag*)(lxb + n*CH + c0);
      float e0 = encs[n*3+0], e1 = encs[n*3+1], e2 = encs[n*3+2];
      #pragma unroll
      for (int j = 0; j < 8; j++) {
        float xf = bf16_to_f((ushort_t)xv[j]);
        av0[j] = fmaf(e0, xf, av0[j]);
        av1[j] = fmaf(e1, xf, av1[j]);
        av2[j] = fmaf(e2, xf, av2[j]);
      }
    }
    bfrag o0, o1, o2;
    #pragma unroll
    for (int j = 0; j < 8; j++) {
      o0[j] = (short)bf16_rne(av0[j]);
      o1[j] = (short)bf16_rne(av1[j]);
      o2[j] = (short)bf16_rne(av2[j]);
    }
    *(bfrag*)(u_pre + ((size_t)b*3 + 0)*CH + c0) = o0;
    *(bfrag*)(u_pre + ((size_t)b*3 + 1)*CH + c0) = o1;
    *(bfrag*)(u_pre + ((size_t)b*3 + 2)*CH + c0) = o2;
  }
}

// ---------------------------------------------------------------------------
// bf16 MFMA GEMM (m97 structure): C[m,d] = sum_c A[m,c]*B[d,c]
// ---------------------------------------------------------------------------
#define GM 1536
#define GK 2048
#define GN 2048

template<int MODE>
__global__ __launch_bounds__(256) void gemm_mfma(
    const ushort_t* __restrict__ A, const ushort_t* __restrict__ B,
    void* __restrict__ Cout, const float* __restrict__ bias,
    const float* __restrict__ gamma, const float* __restrict__ beta)
{
  __shared__ ushort_t Asm[128*64];   // 16 KB, [row][k] linear
  __shared__ ushort_t Bsm[128*64];   // 16 KB, [col][k] linear
  const int tid  = threadIdx.x;
  const int lane = tid & 63, wv = tid >> 6;
  const int mb = blockIdx.x % (GM/128), nb = blockIdx.x / (GM/128);
  const int wr = (wv >> 1) * 64, wc = (wv & 1) * 64;   // wave quadrant

  f32x4v acc[4][4];
  #pragma unroll
  for (int m = 0; m < 4; m++)
    #pragma unroll
    for (int n = 0; n < 4; n++)
      acc[m][n] = (f32x4v){0.f, 0.f, 0.f, 0.f};

  const int ldrow = tid >> 3;        // 0..31 within each 32-row chunk
  const int ldcol = (tid & 7) * 8;   // element col within BK=64
  const ushort_t* Ag = A + (size_t)(mb*128 + 0)*GK;
  const ushort_t* Bg = B + (size_t)(nb*128 + 0)*GK;
  const int r15 = lane & 15, khi = lane >> 4;

  for (int k0 = 0; k0 < GK; k0 += 64) {
    __syncthreads();
    #pragma unroll
    for (int i = 0; i < 4; i++) {
      const ushort_t* ga = Ag + (size_t)(i*32 + ldrow)*GK + k0 + ldcol;
      const ushort_t* gb = Bg + (size_t)(i*32 + ldrow)*GK + k0 + ldcol;
      __builtin_amdgcn_global_load_lds(
          (const __attribute__((address_space(1))) void*)ga,
          (__attribute__((address_space(3))) void*)(Asm + i*2048 + wv*512),
          16, 0, 0);
      __builtin_amdgcn_global_load_lds(
          (const __attribute__((address_space(1))) void*)gb,
          (__attribute__((address_space(3))) void*)(Bsm + i*2048 + wv*512),
          16, 0, 0);
    }
    asm volatile("s_waitcnt vmcnt(0)" ::: "memory");
    __syncthreads();

    #pragma unroll
    for (int ks = 0; ks < 2; ks++) {
      bfrag af[4], bfv[4];
      #pragma unroll
      for (int m = 0; m < 4; m++)
        af[m] = *(const bfrag*)(Asm + (wr + m*16 + r15)*64 + ks*32 + khi*8);
      #pragma unroll
      for (int n = 0; n < 4; n++)
        bfv[n] = *(const bfrag*)(Bsm + (wc + n*16 + r15)*64 + ks*32 + khi*8);
      #pragma unroll
      for (int m = 0; m < 4; m++)
        #pragma unroll
        for (int n = 0; n < 4; n++)
          acc[m][n] = __builtin_amdgcn_mfma_f32_16x16x32_bf16(
              af[m], bfv[n], acc[m][n], 0, 0, 0);
    }
  }

  #pragma unroll
  for (int n = 0; n < 4; n++) {
    const int gc = nb*128 + wc + n*16 + r15;
    float bi = 0.f, ga = 0.f, be = 0.f;
    if (MODE == 1) { bi = bias[gc]; ga = gamma[gc]*BNS; be = beta[gc]; }
    #pragma unroll
    for (int m = 0; m < 4; m++) {
      const int gr0 = mb*128 + wr + m*16 + khi*4;
      #pragma unroll
      for (int r = 0; r < 4; r++) {
        float v = acc[m][n][r];
        if (MODE == 1) {
          v = fmaxf(fmaf(v + bi, ga, be), 0.f);
          ((ushort_t*)Cout)[(size_t)(gr0 + r)*GN + gc] = bf16_rne(v);
        } else {
          ((float*)Cout)[(size_t)(gr0 + r)*GN + gc] = v;
        }
      }
    }
  }
}

// ---------------------------------------------------------------------------
// Epilogue: y[b,n,d] = relu((sum_k dec[b,n,k]*V[b,k,d] + b3[d])*g3s[d]+be3[d]) + x
// ---------------------------------------------------------------------------
__global__ __launch_bounds__(256) void k_epi(
    const float* __restrict__ x, const float* __restrict__ V,
    const float* __restrict__ dec, const float* __restrict__ b3,
    const float* __restrict__ g3, const float* __restrict__ be3,
    float* __restrict__ y)
{
  __shared__ float4 lv[3*512];
  __shared__ float4 lmul[512], ladd[512];
  __shared__ float ld[54];
  const int b = blockIdx.x, tid = threadIdx.x;

  const float4* v4 = (const float4*)(V + (size_t)b*3*CH);
  for (int i = tid; i < 1536; i += 256) lv[i] = v4[i];
  const float4* g34  = (const float4*)g3;
  const float4* b34  = (const float4*)b3;
  const float4* be34 = (const float4*)be3;
  for (int i = tid; i < 512; i += 256) {
    float4 g = g34[i], bb = b34[i], be = be34[i];
    float4 mu, ad;
    mu.x = g.x*BNS; mu.y = g.y*BNS; mu.z = g.z*BNS; mu.w = g.w*BNS;
    ad.x = fmaf(bb.x, mu.x, be.x); ad.y = fmaf(bb.y, mu.y, be.y);
    ad.z = fmaf(bb.z, mu.z, be.z); ad.w = fmaf(bb.w, mu.w, be.w);
    lmul[i] = mu; ladd[i] = ad;
  }
  if (tid < 54) ld[tid] = dec[(size_t)b*54 + tid];
  __syncthreads();

  for (int r = 0; r < NPTS; r++) {
    float d0 = ld[r*3+0], d1 = ld[r*3+1], d2 = ld[r*3+2];
    const float4* xr = (const float4*)(x + ((size_t)b*NPTS + r)*CH);
    float4* yr = (float4*)(y + ((size_t)b*NPTS + r)*CH);
    for (int i = tid; i < 512; i += 256) {
      float4 v0 = lv[i], v1 = lv[512+i], v2 = lv[1024+i];
      float4 mu = lmul[i], ad = ladd[i], xa = xr[i];
      float4 o;
      o.x = fmaxf(fmaf(fmaf(d0,v0.x, fmaf(d1,v1.x, d2*v2.x)), mu.x, ad.x), 0.f) + xa.x;
      o.y = fmaxf(fmaf(fmaf(d0,v0.y, fmaf(d1,v1.y, d2*v2.y)), mu.y, ad.y), 0.f) + xa.y;
      o.z = fmaxf(fmaf(fmaf(d0,v0.z, fmaf(d1,v1.z, d2*v2.z)), mu.z, ad.z), 0.f) + xa.z;
      o.w = fmaxf(fmaf(fmaf(d0,v0.w, fmaf(d1,v1.w, d2*v2.w)), mu.w, ad.w), 0.f) + xa.w;
      yr[i] = o;
    }
  }
}

// ---------------------------------------------------------------------------
extern "C" void kernel_launch(void* const* d_in, const int* in_sizes, int n_in,
                              void* d_out, int out_size, void* d_ws, size_t ws_size,
                              hipStream_t stream) {
  const float* x   = (const float*)d_in[0];
  const float* pc  = (const float*)d_in[1];
  const float* w1  = (const float*)d_in[2];
  const float* b1  = (const float*)d_in[3];
  const float* w2a = (const float*)d_in[4];
  const float* b2a = (const float*)d_in[5];
  const float* g2  = (const float*)d_in[6];
  const float* be2 = (const float*)d_in[7];
  const float* w2b = (const float*)d_in[8];
  const float* b2b = (const float*)d_in[9];
  const float* wc  = (const float*)d_in[10];
  const float* bc  = (const float*)d_in[11];
  const float* gc  = (const float*)d_in[12];
  const float* bec = (const float*)d_in[13];
  const float* w3  = (const float*)d_in[14];
  const float* b3  = (const float*)d_in[15];
  const float* g3  = (const float*)d_in[16];
  const float* be3 = (const float*)d_in[17];

  float* out = (float*)d_out;
  float* y   = out;
  float* d21 = out + (size_t)BS*NPTS*CH;
  float* d11 = d21 + (size_t)BS*NPTS*NPTS;
  float* d22 = d11 + (size_t)BS*NPTS*NPTS;
  float* d12 = d22 + (size_t)BS*NPTS*NPTS;

  // Scratch in the dead-until-epilogue y region (75.5 MB available):
  char* ybytes = (char*)y;
  ushort_t* u_pre_bf = (ushort_t*)(ybytes + 0);          // 6.29 MB
  ushort_t* u_bf     = (ushort_t*)(ybytes + 6291456);    // 6.29 MB
  ushort_t* wc_bf    = (ushort_t*)(ybytes + 12582912);   // 8.39 MB
  ushort_t* w3_bf    = (ushort_t*)(ybytes + 20971520);   // 8.39 MB (end 29.4 MB)

  // V and dec must survive into the epilogue -> workspace.
  float* V    = (float*)d_ws;               // 512*3*2048 floats
  float* decb = V + (size_t)BS*3*CH;        // 512*54 floats

  f32_to_bf16_k<<<(GK*GN/4 + 255)/256, 256, 0, stream>>>(wc, wc_bf, GK*GN/4);
  f32_to_bf16_k<<<(GK*GN/4 + 255)/256, 256, 0, stream>>>(w3, w3_bf, GK*GN/4);
  k1_batch<<<BS, 256, 0, stream>>>(x, pc, w1, b1, w2a, b2a, g2, be2, w2b, b2b,
                                   d21, d11, d22, d12, u_pre_bf, decb);
  gemm_mfma<1><<<(GM/128)*(GN/128), 256, 0, stream>>>(u_pre_bf, wc_bf, u_bf, bc, gc, bec);
  gemm_mfma<0><<<(GM/128)*(GN/128), 256, 0, stream>>>(u_bf, w3_bf, V, nullptr, nullptr, nullptr);
  k_epi<<<BS, 256, 0, stream>>>(x, V, decb, b3, g3, be3, y);
}

// Round 4
// 178.757 us; speedup vs baseline: 3.3419x; 1.0069x over previous
//
#include <hip/hip_runtime.h>

#define BS   512
#define NPTS 18
#define CH   2048
#define EPSF 1e-12f
#define BNS  0.9999950000374997f   // 1/sqrt(1+1e-5)

typedef unsigned short ushort_t;
typedef __attribute__((ext_vector_type(8)))  short bfrag;   // 8 bf16 (4 VGPRs)
typedef __attribute__((ext_vector_type(4)))  float f32x4v;  // MFMA 16x16 C/D
typedef __attribute__((ext_vector_type(16))) float f32x16;  // MFMA 32x32 C/D

__device__ inline ushort_t bf16_rne(float f) {
  union { float f; unsigned int u; } c; c.f = f;
  unsigned int u = c.u;
  u += 0x7fffu + ((u >> 16) & 1u);
  return (ushort_t)(u >> 16);
}
__device__ inline float bf16_to_f(ushort_t s) {
  union { float f; unsigned int u; } c; c.u = ((unsigned int)s) << 16;
  return c.f;
}

// ---------------------------------------------------------------------------
// Fused f32 -> bf16 cast for wc and w3 (one launch). n4 elements-of-4 each.
// ---------------------------------------------------------------------------
__global__ __launch_bounds__(256) void cast2_k(
    const float* __restrict__ a, const float* __restrict__ b,
    ushort_t* __restrict__ oa, ushort_t* __restrict__ ob, int n4)
{
  int gid = blockIdx.x * 256 + threadIdx.x;
  const float* src; ushort_t* dst; int i;
  if (gid < n4) { src = a; dst = oa; i = gid; }
  else          { src = b; dst = ob; i = gid - n4; if (i >= n4) return; }
  float4 v = ((const float4*)src)[i];
  ushort4 o;
  o.x = bf16_rne(v.x); o.y = bf16_rne(v.y);
  o.z = bf16_rne(v.z); o.w = bf16_rne(v.w);
  ((ushort4*)dst)[i] = o;
}

// ---------------------------------------------------------------------------
// Kernel 1: per-batch small ops. One block per batch, 512 threads (8 waves).
// x[b] staged as bf16 XOR-swizzled (72KB -> 2 blocks/CU -> 16 waves/CU).
//   waves 0-1 : Gram G = X X^T via mfma_32x32x16_bf16 (K split across waves)
//   waves 2-4 : z2 logits (conv2 path, h fused)
//   waves 5-7 : l1 logits (x . w1^T)
// then softmax / distances / enc / u_pre on all threads.
// LDS swizzle: byte_addr ^= (row&7)<<4 on every lxb access (write + reads).
// ---------------------------------------------------------------------------
__global__ __launch_bounds__(512, 4) void k1_batch(
    const float* __restrict__ x, const float* __restrict__ pc,
    const float* __restrict__ w1, const float* __restrict__ b1,
    const float* __restrict__ w2a, const float* __restrict__ b2a,
    const float* __restrict__ g2, const float* __restrict__ be2,
    const float* __restrict__ w2b, const float* __restrict__ b2b,
    float* __restrict__ d21, float* __restrict__ d11,
    float* __restrict__ d22, float* __restrict__ d12,
    ushort_t* __restrict__ u_pre, float* __restrict__ dec_out)
{
  __shared__ __align__(16) ushort_t lxb[NPTS*CH];   // 73728 B (bf16 X, swizzled)
  __shared__ ushort_t Gtmp[16*64];                  // 2048 B (wave1 Gram partials)
  __shared__ float G[NPTS*NPTS];
  __shared__ float l1[NPTS*3], l2[NPTS*3];
  __shared__ float z1s[NPTS*3], z2s[NPTS*3], encs[NPTS*3];
  __shared__ float pcs[NPTS*4], ycs[NPTS], xcs[NPTS];
  __shared__ float red[3*54], red2[3*54];
  __shared__ float n1inv[NPTS], n2inv[NPTS], rinv[NPTS], colinv[3];

  const int b = blockIdx.x, tid = threadIdx.x;
  const int lane = tid & 63, wv = tid >> 6;

  // ---- Phase A: stage x[b] as bf16 (swizzled), load pc[b] ----
  {
    const float4* xb4 = (const float4*)(x + (size_t)b*NPTS*CH);
    for (int i = tid; i < NPTS*CH/4; i += 512) {
      float4 v = xb4[i];
      ushort4 o;
      o.x = bf16_rne(v.x); o.y = bf16_rne(v.y);
      o.z = bf16_rne(v.z); o.w = bf16_rne(v.w);
      int row = i >> 9;                              // (i*8)/4096
      int addr = (i*8) ^ ((row & 7) << 4);
      *(ushort4*)((char*)lxb + addr) = o;
    }
    if (tid < NPTS*4) pcs[tid] = pc[(size_t)b*NPTS*4 + tid];
    if (tid < NPTS) {
      const float* p = pc + (size_t)b*NPTS*4 + tid*4;
      ycs[tid] = p[0] + floorf(p[2]*0.5f);
      xcs[tid] = p[1] + floorf(p[3]*0.5f);
    }
  }
  __syncthreads();   // S1

  float gsum[16];

  if (wv < 2) {
    // ---- Waves 0-1: Gram via MFMA, K halves split across the two waves ----
    const int rc = lane & 31;            // A-row / B-col
    const int kh = lane >> 5;            // k-half within a 16-step
    const int rr = (rc < NPTS) ? rc : (NPTS-1);   // clamp: dup row17 -> unused C rows
    const int base = rr*4096 + wv*2048 + kh*16;   // byte addr before swizzle
    const int m = (rr & 7) << 4;
    f32x16 acc0 = {0.f,0.f,0.f,0.f,0.f,0.f,0.f,0.f,0.f,0.f,0.f,0.f,0.f,0.f,0.f,0.f};
    f32x16 acc1 = acc0;
    #pragma unroll 4
    for (int j = 0; j < 64; j++) {
      int addr = (base + (j << 5)) ^ m;
      bfrag xv = *(const bfrag*)((const char*)lxb + addr);
      if (j & 1) acc1 = __builtin_amdgcn_mfma_f32_32x32x16_bf16(xv, xv, acc1, 0, 0, 0);
      else       acc0 = __builtin_amdgcn_mfma_f32_32x32x16_bf16(xv, xv, acc0, 0, 0, 0);
    }
    #pragma unroll
    for (int r = 0; r < 16; r++) gsum[r] = acc0[r] + acc1[r];
    if (wv == 1) {
      #pragma unroll
      for (int r = 0; r < 16; r++) Gtmp[r*64 + lane] = bf16_rne(gsum[r]);
    }
  } else if (wv < 5) {
    // ---- Waves 2-4: z2 logits (h fused, never materialized) ----
    const int idx = tid - 128;           // 0..191
    float p[NPTS][3];
    #pragma unroll
    for (int n = 0; n < NPTS; n++) { p[n][0]=0.f; p[n][1]=0.f; p[n][2]=0.f; }
    for (int it = 0; it < 11; it++) {
      int c = idx + it*192;
      if (c < CH) {
        const float4 wa = *(const float4*)(w2a + (size_t)c*4);
        const float bb = b2a[c];
        const float gg = g2[c]*BNS, be = be2[c];
        const float wb0 = w2b[c], wb1 = w2b[CH+c], wb2 = w2b[2*CH+c];
        #pragma unroll
        for (int n = 0; n < NPTS; n++) {
          float v = fmaf(pcs[n*4+3], wa.w,
                    fmaf(pcs[n*4+2], wa.z,
                    fmaf(pcs[n*4+1], wa.y,
                    fmaf(pcs[n*4+0], wa.x, bb))));
          float h = fmaxf(fmaf(v, gg, be), 0.f);
          p[n][0] = fmaf(h, wb0, p[n][0]);
          p[n][1] = fmaf(h, wb1, p[n][1]);
          p[n][2] = fmaf(h, wb2, p[n][2]);
        }
      }
    }
    #pragma unroll
    for (int n = 0; n < NPTS; n++)
      #pragma unroll
      for (int k = 0; k < 3; k++) {
        float v = p[n][k];
        #pragma unroll
        for (int off = 32; off; off >>= 1) v += __shfl_xor(v, off);
        if (lane == 0) red[(wv-2)*54 + n*3 + k] = v;
      }
  } else {
    // ---- Waves 5-7: l1 logits = x . w1^T (x from swizzled bf16 LDS) ----
    const int idx = tid - 320;           // 0..191
    float q[NPTS][3];
    #pragma unroll
    for (int n = 0; n < NPTS; n++) { q[n][0]=0.f; q[n][1]=0.f; q[n][2]=0.f; }
    for (int it = 0; it < 11; it++) {
      int c = idx + it*192;
      if (c < CH) {
        float w10 = w1[c], w11 = w1[CH + c], w12 = w1[2*CH + c];
        #pragma unroll
        for (int n = 0; n < NPTS; n++) {
          int addr = (n*4096 + c*2) ^ ((n & 7) << 4);
          float xf = bf16_to_f(*(const ushort_t*)((const char*)lxb + addr));
          q[n][0] = fmaf(xf, w10, q[n][0]);
          q[n][1] = fmaf(xf, w11, q[n][1]);
          q[n][2] = fmaf(xf, w12, q[n][2]);
        }
      }
    }
    #pragma unroll
    for (int n = 0; n < NPTS; n++)
      #pragma unroll
      for (int k = 0; k < 3; k++) {
        float v = q[n][k];
        #pragma unroll
        for (int off = 32; off; off >>= 1) v += __shfl_xor(v, off);
        if (lane == 0) red2[(wv-5)*54 + n*3 + k] = v;
      }
  }
  __syncthreads();   // S2

  // ---- combine partials ----
  if (wv == 0) {
    const int rc = lane & 31, kh = lane >> 5;
    #pragma unroll
    for (int r = 0; r < 16; r++) {
      int orow = (r & 3) + 8*(r >> 2) + 4*kh;
      if (orow < NPTS && rc < NPTS)
        G[orow*NPTS + rc] = gsum[r] + bf16_to_f(Gtmp[r*64 + lane]);
    }
  } else if (tid >= 128 && tid < 182) {
    int t = tid - 128;
    l2[t] = red[t] + red[54+t] + red[108+t] + b2b[t%3];
  } else if (tid >= 192 && tid < 246) {
    int t = tid - 192;
    l1[t] = red2[t] + red2[54+t] + red2[108+t];
  }
  __syncthreads();   // S3

  // ---- softmaxes, norms, dec ----
  if (tid < NPTS) {
    int n = tid;
    float a0 = l1[n*3+0] + b1[0], a1 = l1[n*3+1] + b1[1], a2 = l1[n*3+2] + b1[2];
    float mx = fmaxf(a0, fmaxf(a1, a2));
    float e0 = expf(a0-mx), e1 = expf(a1-mx), e2 = expf(a2-mx);
    float inv = 1.f/(e0+e1+e2);
    float z10 = e0*inv, z11 = e1*inv, z12 = e2*inv;
    z1s[n*3+0]=z10; z1s[n*3+1]=z11; z1s[n*3+2]=z12;
    n1inv[n] = 1.f/fmaxf(sqrtf(z10*z10+z11*z11+z12*z12), EPSF);

    float c0 = l2[n*3+0], c1 = l2[n*3+1], c2 = l2[n*3+2];
    mx = fmaxf(c0, fmaxf(c1, c2));
    e0 = expf(c0-mx); e1 = expf(c1-mx); e2 = expf(c2-mx);
    inv = 1.f/(e0+e1+e2);
    float z20 = e0*inv, z21 = e1*inv, z22 = e2*inv;
    z2s[n*3+0]=z20; z2s[n*3+1]=z21; z2s[n*3+2]=z22;
    n2inv[n] = 1.f/fmaxf(sqrtf(z20*z20+z21*z21+z22*z22), EPSF);

    float zr0 = z10+z20, zr1 = z11+z21, zr2 = z12+z22;
    float rinvv = 1.f/((zr0+zr1+zr2) + EPSF);
    dec_out[(size_t)b*54 + n*3 + 0] = zr0*rinvv;
    dec_out[(size_t)b*54 + n*3 + 1] = zr1*rinvv;
    dec_out[(size_t)b*54 + n*3 + 2] = zr2*rinvv;

    rinv[n] = 1.f/fmaxf(sqrtf(G[n*NPTS+n]), EPSF);
  }
  __syncthreads();   // S4

  if (tid < 3) {
    float s = 0.f;
    #pragma unroll
    for (int n = 0; n < NPTS; n++) s += z1s[n*3+tid] + z2s[n*3+tid];
    colinv[tid] = 1.f/(s + EPSF);
  }
  if (tid < NPTS*NPTS) {
    int t = tid;
    int n = t/NPTS, mm = t - n*NPTS;
    float dd21 = (z1s[n*3]*z1s[mm*3] + z1s[n*3+1]*z1s[mm*3+1] + z1s[n*3+2]*z1s[mm*3+2])
                 * n1inv[n]*n1inv[mm];
    float dd22 = (z2s[n*3]*z2s[mm*3] + z2s[n*3+1]*z2s[mm*3+1] + z2s[n*3+2]*z2s[mm*3+2])
                 * n2inv[n]*n2inv[mm];
    float dd11 = G[t] * rinv[n]*rinv[mm];
    float dyv = ycs[mm]-ycs[n], dxv = xcs[mm]-xcs[n];
    float r = dxv*dxv + dyv*dyv;
    float dd12 = 1.f - 2.f*((r > 0.f) ? sqrtf(r) : 0.f);
    size_t o = (size_t)b*NPTS*NPTS + t;
    d21[o] = dd21; d11[o] = dd11; d22[o] = dd22; d12[o] = dd12;
  }
  __syncthreads();   // S5
  if (tid < 54) encs[tid] = (z1s[tid]+z2s[tid])*colinv[tid%3];
  __syncthreads();   // S6

  // ---- u_pre[k,c] = sum_n enc[n,k]*x[n,c]  (512 thr x 4 ch, bf16 out) ----
  {
    const int c0 = tid*4;
    float av0[4], av1[4], av2[4];
    #pragma unroll
    for (int j = 0; j < 4; j++) { av0[j]=0.f; av1[j]=0.f; av2[j]=0.f; }
    for (int n = 0; n < NPTS; n++) {
      int addr = (n*4096 + c0*2) ^ ((n & 7) << 4);
      ushort4 xv = *(const ushort4*)((const char*)lxb + addr);
      float e0 = encs[n*3+0], e1 = encs[n*3+1], e2 = encs[n*3+2];
      float xf0 = bf16_to_f(xv.x), xf1 = bf16_to_f(xv.y);
      float xf2 = bf16_to_f(xv.z), xf3 = bf16_to_f(xv.w);
      av0[0]=fmaf(e0,xf0,av0[0]); av0[1]=fmaf(e0,xf1,av0[1]);
      av0[2]=fmaf(e0,xf2,av0[2]); av0[3]=fmaf(e0,xf3,av0[3]);
      av1[0]=fmaf(e1,xf0,av1[0]); av1[1]=fmaf(e1,xf1,av1[1]);
      av1[2]=fmaf(e1,xf2,av1[2]); av1[3]=fmaf(e1,xf3,av1[3]);
      av2[0]=fmaf(e2,xf0,av2[0]); av2[1]=fmaf(e2,xf1,av2[1]);
      av2[2]=fmaf(e2,xf2,av2[2]); av2[3]=fmaf(e2,xf3,av2[3]);
    }
    ushort4 o0, o1, o2;
    o0.x=bf16_rne(av0[0]); o0.y=bf16_rne(av0[1]); o0.z=bf16_rne(av0[2]); o0.w=bf16_rne(av0[3]);
    o1.x=bf16_rne(av1[0]); o1.y=bf16_rne(av1[1]); o1.z=bf16_rne(av1[2]); o1.w=bf16_rne(av1[3]);
    o2.x=bf16_rne(av2[0]); o2.y=bf16_rne(av2[1]); o2.z=bf16_rne(av2[2]); o2.w=bf16_rne(av2[3]);
    *(ushort4*)(u_pre + ((size_t)b*3 + 0)*CH + c0) = o0;
    *(ushort4*)(u_pre + ((size_t)b*3 + 1)*CH + c0) = o1;
    *(ushort4*)(u_pre + ((size_t)b*3 + 2)*CH + c0) = o2;
  }
}

// ---------------------------------------------------------------------------
// bf16 MFMA GEMM (m97 structure): C[m,d] = sum_c A[m,c]*B[d,c]
// ---------------------------------------------------------------------------
#define GM 1536
#define GK 2048
#define GN 2048

template<int MODE>
__global__ __launch_bounds__(256) void gemm_mfma(
    const ushort_t* __restrict__ A, const ushort_t* __restrict__ B,
    void* __restrict__ Cout, const float* __restrict__ bias,
    const float* __restrict__ gamma, const float* __restrict__ beta)
{
  __shared__ ushort_t Asm[128*64];   // 16 KB, [row][k] linear
  __shared__ ushort_t Bsm[128*64];   // 16 KB, [col][k] linear
  const int tid  = threadIdx.x;
  const int lane = tid & 63, wv = tid >> 6;
  const int mb = blockIdx.x % (GM/128), nb = blockIdx.x / (GM/128);
  const int wr = (wv >> 1) * 64, wc = (wv & 1) * 64;   // wave quadrant

  f32x4v acc[4][4];
  #pragma unroll
  for (int m = 0; m < 4; m++)
    #pragma unroll
    for (int n = 0; n < 4; n++)
      acc[m][n] = (f32x4v){0.f, 0.f, 0.f, 0.f};

  const int ldrow = tid >> 3;        // 0..31 within each 32-row chunk
  const int ldcol = (tid & 7) * 8;   // element col within BK=64
  const ushort_t* Ag = A + (size_t)(mb*128 + 0)*GK;
  const ushort_t* Bg = B + (size_t)(nb*128 + 0)*GK;
  const int r15 = lane & 15, khi = lane >> 4;

  for (int k0 = 0; k0 < GK; k0 += 64) {
    __syncthreads();
    #pragma unroll
    for (int i = 0; i < 4; i++) {
      const ushort_t* ga = Ag + (size_t)(i*32 + ldrow)*GK + k0 + ldcol;
      const ushort_t* gb = Bg + (size_t)(i*32 + ldrow)*GK + k0 + ldcol;
      __builtin_amdgcn_global_load_lds(
          (const __attribute__((address_space(1))) void*)ga,
          (__attribute__((address_space(3))) void*)(Asm + i*2048 + wv*512),
          16, 0, 0);
      __builtin_amdgcn_global_load_lds(
          (const __attribute__((address_space(1))) void*)gb,
          (__attribute__((address_space(3))) void*)(Bsm + i*2048 + wv*512),
          16, 0, 0);
    }
    asm volatile("s_waitcnt vmcnt(0)" ::: "memory");
    __syncthreads();

    #pragma unroll
    for (int ks = 0; ks < 2; ks++) {
      bfrag af[4], bfv[4];
      #pragma unroll
      for (int m = 0; m < 4; m++)
        af[m] = *(const bfrag*)(Asm + (wr + m*16 + r15)*64 + ks*32 + khi*8);
      #pragma unroll
      for (int n = 0; n < 4; n++)
        bfv[n] = *(const bfrag*)(Bsm + (wc + n*16 + r15)*64 + ks*32 + khi*8);
      #pragma unroll
      for (int m = 0; m < 4; m++)
        #pragma unroll
        for (int n = 0; n < 4; n++)
          acc[m][n] = __builtin_amdgcn_mfma_f32_16x16x32_bf16(
              af[m], bfv[n], acc[m][n], 0, 0, 0);
    }
  }

  #pragma unroll
  for (int n = 0; n < 4; n++) {
    const int gc = nb*128 + wc + n*16 + r15;
    float bi = 0.f, ga = 0.f, be = 0.f;
    if (MODE == 1) { bi = bias[gc]; ga = gamma[gc]*BNS; be = beta[gc]; }
    #pragma unroll
    for (int m = 0; m < 4; m++) {
      const int gr0 = mb*128 + wr + m*16 + khi*4;
      #pragma unroll
      for (int r = 0; r < 4; r++) {
        float v = acc[m][n][r];
        if (MODE == 1) {
          v = fmaxf(fmaf(v + bi, ga, be), 0.f);
          ((ushort_t*)Cout)[(size_t)(gr0 + r)*GN + gc] = bf16_rne(v);
        } else {
          ((float*)Cout)[(size_t)(gr0 + r)*GN + gc] = v;
        }
      }
    }
  }
}

// ---------------------------------------------------------------------------
// Epilogue: y[b,n,d] = relu((sum_k dec[b,n,k]*V[b,k,d] + b3[d])*g3s[d]+be3[d]) + x
// ---------------------------------------------------------------------------
__global__ __launch_bounds__(256) void k_epi(
    const float* __restrict__ x, const float* __restrict__ V,
    const float* __restrict__ dec, const float* __restrict__ b3,
    const float* __restrict__ g3, const float* __restrict__ be3,
    float* __restrict__ y)
{
  __shared__ float4 lv[3*512];
  __shared__ float4 lmul[512], ladd[512];
  __shared__ float ld[54];
  const int b = blockIdx.x, tid = threadIdx.x;

  const float4* v4 = (const float4*)(V + (size_t)b*3*CH);
  for (int i = tid; i < 1536; i += 256) lv[i] = v4[i];
  const float4* g34  = (const float4*)g3;
  const float4* b34  = (const float4*)b3;
  const float4* be34 = (const float4*)be3;
  for (int i = tid; i < 512; i += 256) {
    float4 g = g34[i], bb = b34[i], be = be34[i];
    float4 mu, ad;
    mu.x = g.x*BNS; mu.y = g.y*BNS; mu.z = g.z*BNS; mu.w = g.w*BNS;
    ad.x = fmaf(bb.x, mu.x, be.x); ad.y = fmaf(bb.y, mu.y, be.y);
    ad.z = fmaf(bb.z, mu.z, be.z); ad.w = fmaf(bb.w, mu.w, be.w);
    lmul[i] = mu; ladd[i] = ad;
  }
  if (tid < 54) ld[tid] = dec[(size_t)b*54 + tid];
  __syncthreads();

  for (int r = 0; r < NPTS; r++) {
    float d0 = ld[r*3+0], d1 = ld[r*3+1], d2 = ld[r*3+2];
    const float4* xr = (const float4*)(x + ((size_t)b*NPTS + r)*CH);
    float4* yr = (float4*)(y + ((size_t)b*NPTS + r)*CH);
    for (int i = tid; i < 512; i += 256) {
      float4 v0 = lv[i], v1 = lv[512+i], v2 = lv[1024+i];
      float4 mu = lmul[i], ad = ladd[i], xa = xr[i];
      float4 o;
      o.x = fmaxf(fmaf(fmaf(d0,v0.x, fmaf(d1,v1.x, d2*v2.x)), mu.x, ad.x), 0.f) + xa.x;
      o.y = fmaxf(fmaf(fmaf(d0,v0.y, fmaf(d1,v1.y, d2*v2.y)), mu.y, ad.y), 0.f) + xa.y;
      o.z = fmaxf(fmaf(fmaf(d0,v0.z, fmaf(d1,v1.z, d2*v2.z)), mu.z, ad.z), 0.f) + xa.z;
      o.w = fmaxf(fmaf(fmaf(d0,v0.w, fmaf(d1,v1.w, d2*v2.w)), mu.w, ad.w), 0.f) + xa.w;
      yr[i] = o;
    }
  }
}

// ---------------------------------------------------------------------------
extern "C" void kernel_launch(void* const* d_in, const int* in_sizes, int n_in,
                              void* d_out, int out_size, void* d_ws, size_t ws_size,
                              hipStream_t stream) {
  const float* x   = (const float*)d_in[0];
  const float* pc  = (const float*)d_in[1];
  const float* w1  = (const float*)d_in[2];
  const float* b1  = (const float*)d_in[3];
  const float* w2a = (const float*)d_in[4];
  const float* b2a = (const float*)d_in[5];
  const float* g2  = (const float*)d_in[6];
  const float* be2 = (const float*)d_in[7];
  const float* w2b = (const float*)d_in[8];
  const float* b2b = (const float*)d_in[9];
  const float* wc  = (const float*)d_in[10];
  const float* bc  = (const float*)d_in[11];
  const float* gc  = (const float*)d_in[12];
  const float* bec = (const float*)d_in[13];
  const float* w3  = (const float*)d_in[14];
  const float* b3  = (const float*)d_in[15];
  const float* g3  = (const float*)d_in[16];
  const float* be3 = (const float*)d_in[17];

  float* out = (float*)d_out;
  float* y   = out;
  float* d21 = out + (size_t)BS*NPTS*CH;
  float* d11 = d21 + (size_t)BS*NPTS*NPTS;
  float* d22 = d11 + (size_t)BS*NPTS*NPTS;
  float* d12 = d22 + (size_t)BS*NPTS*NPTS;

  // Scratch in the dead-until-epilogue y region (75.5 MB available):
  char* ybytes = (char*)y;
  ushort_t* u_pre_bf = (ushort_t*)(ybytes + 0);          // 6.29 MB
  ushort_t* u_bf     = (ushort_t*)(ybytes + 6291456);    // 6.29 MB
  ushort_t* wc_bf    = (ushort_t*)(ybytes + 12582912);   // 8.39 MB
  ushort_t* w3_bf    = (ushort_t*)(ybytes + 20971520);   // 8.39 MB (end 29.4 MB)

  // V and dec must survive into the epilogue -> workspace.
  float* V    = (float*)d_ws;               // 512*3*2048 floats
  float* decb = V + (size_t)BS*3*CH;        // 512*54 floats

  const int n4 = GK*GN/4;
  cast2_k<<<(2*n4 + 255)/256, 256, 0, stream>>>(wc, w3, wc_bf, w3_bf, n4);
  k1_batch<<<BS, 512, 0, stream>>>(x, pc, w1, b1, w2a, b2a, g2, be2, w2b, b2b,
                                   d21, d11, d22, d12, u_pre_bf, decb);
  gemm_mfma<1><<<(GM/128)*(GN/128), 256, 0, stream>>>(u_pre_bf, wc_bf, u_bf, bc, gc, bec);
  gemm_mfma<0><<<(GM/128)*(GN/128), 256, 0, stream>>>(u_bf, w3_bf, V, nullptr, nullptr, nullptr);
  k_epi<<<BS, 256, 0, stream>>>(x, V, decb, b3, g3, be3, y);
}